// Round 4
// baseline (817.594 us; speedup 1.0000x reference)
//
#include <hip/hip_runtime.h>
#include <cstddef>

typedef unsigned short u16;
typedef __attribute__((ext_vector_type(8))) short bf16x8;   // 8 bf16 in 4 VGPRs
typedef __attribute__((ext_vector_type(4))) float f32x4;

__device__ __forceinline__ u16 f2bf(float f) {
  union { float f; unsigned u; } x; x.f = f;
  unsigned r = x.u + 0x7fffu + ((x.u >> 16) & 1u);   // RNE; inputs are finite
  return (u16)(r >> 16);
}
__device__ __forceinline__ float bf2f(u16 h) {
  union { unsigned u; float f; } x; x.u = ((unsigned)h) << 16;
  return x.f;
}

// async global->LDS, 16 B per lane; LDS dest is wave-uniform base + lane*16
__device__ __forceinline__ void gll16(const u16* g, u16* ldsbase) {
  __builtin_amdgcn_global_load_lds(
      (const __attribute__((address_space(1))) void*)g,
      (__attribute__((address_space(3))) void*)ldsbase, 16, 0, 0);
}

// ---------------------------------------------------------------------------
__global__ __launch_bounds__(256) void f32_to_bf16(const float* __restrict__ in,
                                                   u16* __restrict__ out, size_t n) {
  size_t i = (size_t)blockIdx.x * 256 + threadIdx.x;
  if (i < n) out[i] = f2bf(in[i]);
}

// transpose f32 [R][C] -> bf16 [C][R]   (R,C multiples of 32) grid(C/32, R/32)
__global__ __launch_bounds__(256) void transpose_f32_bf16(const float* __restrict__ in,
                                                          u16* __restrict__ out,
                                                          int R, int C) {
  __shared__ float tile[32][33];
  int c0 = blockIdx.x * 32, r0 = blockIdx.y * 32;
  int tx = threadIdx.x & 31, ty = threadIdx.x >> 5;   // ty: 0..7
  #pragma unroll
  for (int i = ty; i < 32; i += 8)
    tile[i][tx] = in[(size_t)(r0 + i) * C + c0 + tx];
  __syncthreads();
  #pragma unroll
  for (int i = ty; i < 32; i += 8)
    out[(size_t)(c0 + i) * R + r0 + tx] = f2bf(tile[tx][i]);
}

// ---------------------------------------------------------------------------
// Tiled 8-wave GEMM: C[z][M][N] = A[z][M][K] @ Bt[z][N][K]^T, bf16 in, f32 acc.
// BK=64, 512 threads. 256x256 (4-phase) and 256x128 / 128x256 (2-phase).
// R3: trailing-window fragment reads at R1's register budget.
//   MFMA quadrant order Q(0,0),Q(0,1),Q(1,0),Q(1,1) gives lifetimes
//   af: X(ph1-2) then Y(ph3-4); bfr-lo: ph1+ph3; bfr-hi: ph2+ph4, so each
//   operand reloads in the window where its predecessor dies, AFTER the MFMA
//   cluster (reads overlap other waves' MFMAs instead of sitting in the
//   barrier gap; R1 measured ~6300 cyc/K-tile vs ~3000 model from exactly
//   this serialization). Read distribution 4/8/4/8 per phase. Staging
//   schedule, barriers, and vmcnt placement identical to the R1 kernel that
//   passed; one added tail drain (ph3 vmcnt(0) when kt+2==NT) covers the
//   ph3-end cross-buffer read. MFMA K-order per acc element unchanged ->
//   bit-identical results.
// ---------------------------------------------------------------------------
enum { EPI_F32 = 0, EPI_BF16 = 1, EPI_BF16_SCALE = 2,
       EPI_BIAS_RELU_BF16 = 3, EPI_BIAS_F32 = 4 };
enum { MODE_FULL = 0, MODE_TRI = 1, MODE_CAUSAL_K = 2 };

template <int EPI, int MODE, int BM, int BN>
__global__ __launch_bounds__(512) void gemm256(
    const u16* __restrict__ A, const u16* __restrict__ Bt,
    void* __restrict__ C0, const float* __restrict__ bias,
    const u16* __restrict__ A2, const u16* __restrict__ B2, int dsplit,
    int K, int lda, int ldb, int ldc,
    long long sA, long long sB, long long sC)
{
  constexpr int WM  = BM / 128;        // 1 or 2 M-wave groups
  constexpr int WN  = 8 / WM;          // 4 or 8 N-wave groups
  constexpr int CPW = BN / WN;         // cols per wave: 64 or 32
  constexpr int NF  = CPW / 16;        // 4 or 2 n-fragments
  constexpr int nBr = BN / 64;         // B regions (64 rows each)

  __shared__ __align__(16) u16 lA[2][BM * 64];
  __shared__ __align__(16) u16 lB[2][BN * 64];

  // ---- block -> (z, mi, ni), XCD-compact swizzle (all grids %8==0) ----
  const unsigned gx = gridDim.x, gxy = gridDim.x * gridDim.y;
  unsigned id = blockIdx.x + gx * blockIdx.y + gxy * blockIdx.z;
  const unsigned nb = gxy * gridDim.z;
  unsigned p = id;
  if ((nb & 7u) == 0u) p = (id & 7u) * (nb >> 3) + (id >> 3);
  int z, mi, ni;
  if constexpr (MODE == MODE_TRI) {
    z = (int)(p / gxy);                 // gxy == tri blocks per batch
    int r = (int)(p % gxy);
    int m = 0;
    if constexpr (BN == 256) {
      while ((m + 1) * (m + 2) / 2 <= r) m++;
      mi = m; ni = r - m * (m + 1) / 2;
    } else {                            // BN=128: 2mi+2 col-tiles at row mi
      while ((m + 1) * (m + 2) <= r) m++;
      mi = m; ni = r - m * (m + 1);
    }
  } else {
    z = (int)(p / gxy);
    const unsigned rem = p % gxy;
    mi = (int)(rem / gx);
    ni = (int)(rem % gx);
  }
  // dual-source fusion (Q2+K2): upper ni half switches A/B and C offset
  if (dsplit && ni >= dsplit) {
    A = A2; Bt = B2;
    C0 = (void*)((u16*)C0 + (size_t)dsplit * BN);
    ni -= dsplit;
  }
  const int m0 = mi * BM, n0 = ni * BN;

  A  += (long long)z * sA;
  Bt += (long long)z * sB;

  int NT = K >> 6;
  if constexpr (MODE == MODE_CAUSAL_K) NT = (m0 + BM) >> 6;  // P==0 above diag

  const int t    = threadIdx.x;
  const int lane = t & 63;
  const int wave = t >> 6;
  const int wr   = (WM == 1) ? 0 : (wave >> 2);
  const int wc   = (WM == 1) ? wave : (wave & 3);
  const int quad = lane >> 4;
  const int lrow = lane & 15;

  // ---- staging addressing: pre-swizzled global source, linear LDS dest ----
  const int srow = lane >> 3;                    // 0..7 (== row & 7)
  const int scol = ((lane & 7) ^ srow) * 8;      // source granule for phys lane&7
  const u16* gAp = A  + (size_t)(m0 + wave * 8 + srow) * lda + scol;
  const u16* gBp = Bt + (size_t)(n0 + wave * 8 + srow) * ldb + scol;
  const size_t a64 = (size_t)64 * lda, b64 = (size_t)64 * ldb;
  const int lw = wave * 512;           // wave's write base within a 64-row region

  // ---- fragment read addressing (swizzled): phys granule = need ^ (row&7) ----
  const int pg0 = (quad ^ (lrow & 7)) * 8;       // ks=0
  const int pg1 = pg0 ^ 32;                      // ks=1
  const int rA = (wr * 128 + lrow) * 64;
  const int rB = (wc * CPW + lrow) * 64;

  f32x4 acc[8][NF];
  const f32x4 zero = {0.f, 0.f, 0.f, 0.f};
  #pragma unroll
  for (int i = 0; i < 8; i++)
    #pragma unroll
    for (int j = 0; j < NF; j++) acc[i][j] = zero;

  bf16x8 af[4][2];     // A frags: X (rows wr*128+0..63) then Y (+64..127)
  bf16x8 bfr[NF][2];   // B frags

  if constexpr (BM == 256 && BN == 256) {
    // ======================= 4-phase 256x256 path ===========================
    auto stage = [&](int b, int s, int kt) {
      const int k = kt * 64;
      if (s == 0) {
        gll16(gBp + k,            &lB[b][lw]);
        gll16(gBp + k + b64,      &lB[b][4096 + lw]);
      } else if (s == 1) {
        gll16(gBp + k + 2 * b64,  &lB[b][8192 + lw]);
        gll16(gBp + k + 3 * b64,  &lB[b][12288 + lw]);
      } else if (s == 2) {
        gll16(gAp + k,            &lA[b][lw]);
        gll16(gAp + k + a64,      &lA[b][4096 + lw]);
      } else {
        gll16(gAp + k + 2 * a64,  &lA[b][8192 + lw]);
        gll16(gAp + k + 3 * a64,  &lA[b][12288 + lw]);
      }
    };

    stage(0, 0, 0); stage(0, 1, 0); stage(0, 2, 0); stage(0, 3, 0);
    if (NT > 1) {
      stage(1, 0, 1); stage(1, 1, 1); stage(1, 2, 1);
      asm volatile("s_waitcnt vmcnt(6)" ::: "memory");   // tile0 fully landed
    } else {
      asm volatile("s_waitcnt vmcnt(0)" ::: "memory");
    }
    __builtin_amdgcn_s_barrier();
    {
      const u16* s0a = &lA[0][0];
      const u16* s0b = &lB[0][0];
      #pragma unroll
      for (int mf = 0; mf < 4; ++mf) {
        af[mf][0] = *(const bf16x8*)(s0a + rA + mf * 1024 + pg0);
        af[mf][1] = *(const bf16x8*)(s0a + rA + mf * 1024 + pg1);
      }
      #pragma unroll
      for (int nf = 0; nf < 2; ++nf) {
        bfr[nf][0] = *(const bf16x8*)(s0b + rB + nf * 1024 + pg0);
        bfr[nf][1] = *(const bf16x8*)(s0b + rB + nf * 1024 + pg1);
      }
    }

    for (int kt = 0; kt < NT; ++kt) {
      const int bsel = kt & 1;
      const u16* sa  = &lA[bsel][0];
      const u16* sb  = &lB[bsel][0];
      const u16* sa1 = &lA[bsel ^ 1][0];
      const u16* sb1 = &lB[bsel ^ 1][0];

      // ---- phase 1 : Q(0,0) = X x B-lo ; trail: read B-hi(kt) ----
      if (kt + 1 < NT) stage(bsel ^ 1, 3, kt + 1);
      __builtin_amdgcn_s_barrier();
      asm volatile("s_waitcnt lgkmcnt(0)" ::: "memory");
      __builtin_amdgcn_sched_barrier(0);
      __builtin_amdgcn_s_setprio(1);
      #pragma unroll
      for (int mf = 0; mf < 4; ++mf)
        #pragma unroll
        for (int nf = 0; nf < 2; ++nf) {
          acc[mf][nf] = __builtin_amdgcn_mfma_f32_16x16x32_bf16(bfr[nf][0], af[mf][0], acc[mf][nf], 0, 0, 0);
          acc[mf][nf] = __builtin_amdgcn_mfma_f32_16x16x32_bf16(bfr[nf][1], af[mf][1], acc[mf][nf], 0, 0, 0);
        }
      __builtin_amdgcn_s_setprio(0);
      #pragma unroll
      for (int nf = 2; nf < 4; ++nf) {
        bfr[nf][0] = *(const bf16x8*)(sb + rB + nf * 1024 + pg0);
        bfr[nf][1] = *(const bf16x8*)(sb + rB + nf * 1024 + pg1);
      }
      __builtin_amdgcn_sched_barrier(0);
      __builtin_amdgcn_s_barrier();

      // ---- phase 2 : Q(0,1) = X x B-hi ; trail: read Y(kt) ----
      if (kt + 2 < NT) stage(bsel, 0, kt + 2);
      __builtin_amdgcn_s_barrier();
      asm volatile("s_waitcnt lgkmcnt(0)" ::: "memory");
      __builtin_amdgcn_sched_barrier(0);
      __builtin_amdgcn_s_setprio(1);
      #pragma unroll
      for (int mf = 0; mf < 4; ++mf)
        #pragma unroll
        for (int nf = 0; nf < 2; ++nf) {
          acc[mf][nf + 2] = __builtin_amdgcn_mfma_f32_16x16x32_bf16(bfr[nf + 2][0], af[mf][0], acc[mf][nf + 2], 0, 0, 0);
          acc[mf][nf + 2] = __builtin_amdgcn_mfma_f32_16x16x32_bf16(bfr[nf + 2][1], af[mf][1], acc[mf][nf + 2], 0, 0, 0);
        }
      __builtin_amdgcn_s_setprio(0);
      #pragma unroll
      for (int mf = 0; mf < 4; ++mf) {
        af[mf][0] = *(const bf16x8*)(sa + rA + (mf + 4) * 1024 + pg0);
        af[mf][1] = *(const bf16x8*)(sa + rA + (mf + 4) * 1024 + pg1);
      }
      __builtin_amdgcn_sched_barrier(0);
      __builtin_amdgcn_s_barrier();

      // ---- phase 3 : Q(1,0) = Y x B-lo ; trail: read B-lo(kt+1) ----
      // vmcnt(6): newest 6 = s1(kt+2),s0(kt+2),s3(kt+1) -> s0(kt+1) landed.
      if (kt + 2 < NT) {
        stage(bsel, 1, kt + 2);
        asm volatile("s_waitcnt vmcnt(6)" ::: "memory");
      } else if (kt + 1 < NT) {
        asm volatile("s_waitcnt vmcnt(0)" ::: "memory");   // tail drain
      }
      __builtin_amdgcn_s_barrier();
      asm volatile("s_waitcnt lgkmcnt(0)" ::: "memory");
      __builtin_amdgcn_sched_barrier(0);
      __builtin_amdgcn_s_setprio(1);
      #pragma unroll
      for (int mf = 0; mf < 4; ++mf)
        #pragma unroll
        for (int nf = 0; nf < 2; ++nf) {
          acc[mf + 4][nf] = __builtin_amdgcn_mfma_f32_16x16x32_bf16(bfr[nf][0], af[mf][0], acc[mf + 4][nf], 0, 0, 0);
          acc[mf + 4][nf] = __builtin_amdgcn_mfma_f32_16x16x32_bf16(bfr[nf][1], af[mf][1], acc[mf + 4][nf], 0, 0, 0);
        }
      __builtin_amdgcn_s_setprio(0);
      if (kt + 1 < NT) {
        #pragma unroll
        for (int nf = 0; nf < 2; ++nf) {
          bfr[nf][0] = *(const bf16x8*)(sb1 + rB + nf * 1024 + pg0);
          bfr[nf][1] = *(const bf16x8*)(sb1 + rB + nf * 1024 + pg1);
        }
      }
      __builtin_amdgcn_sched_barrier(0);
      __builtin_amdgcn_s_barrier();

      // ---- phase 4 : Q(1,1) = Y x B-hi ; trail: read X(kt+1) ----
      // vmcnt(6): newest 6 = s2,s1,s0(kt+2) -> s3(kt+1) landed.
      if (kt + 2 < NT) {
        stage(bsel, 2, kt + 2);
        asm volatile("s_waitcnt vmcnt(6)" ::: "memory");
      } else if (kt + 1 < NT) {
        asm volatile("s_waitcnt vmcnt(0)" ::: "memory");
      }
      __builtin_amdgcn_s_barrier();
      __builtin_amdgcn_s_setprio(1);
      #pragma unroll
      for (int mf = 0; mf < 4; ++mf)
        #pragma unroll
        for (int nf = 0; nf < 2; ++nf) {
          acc[mf + 4][nf + 2] = __builtin_amdgcn_mfma_f32_16x16x32_bf16(bfr[nf + 2][0], af[mf][0], acc[mf + 4][nf + 2], 0, 0, 0);
          acc[mf + 4][nf + 2] = __builtin_amdgcn_mfma_f32_16x16x32_bf16(bfr[nf + 2][1], af[mf][1], acc[mf + 4][nf + 2], 0, 0, 0);
        }
      __builtin_amdgcn_s_setprio(0);
      if (kt + 1 < NT) {
        #pragma unroll
        for (int mf = 0; mf < 4; ++mf) {
          af[mf][0] = *(const bf16x8*)(sa1 + rA + mf * 1024 + pg0);
          af[mf][1] = *(const bf16x8*)(sa1 + rA + mf * 1024 + pg1);
        }
      }
      __builtin_amdgcn_sched_barrier(0);
      __builtin_amdgcn_s_barrier();
    }
  } else {
    // ======================= 2-phase narrow-tile path =======================
    // 6 regions (64x64, 8 KB): 0..nBr-1 = B, nBr..5 = A.
    // half0 = regions {0,1,2}; half1 = {3,4,5}.
    auto stage3 = [&](int b, int h, int kt) {
      const int k = kt * 64;
      #pragma unroll
      for (int s = 0; s < 3; ++s) {
        const int rg = h * 3 + s;
        if (rg < nBr) gll16(gBp + k + (size_t)rg * b64, &lB[b][rg * 4096 + lw]);
        else          gll16(gAp + k + (size_t)(rg - nBr) * a64, &lA[b][(rg - nBr) * 4096 + lw]);
      }
    };

    stage3(0, 0, 0); stage3(0, 1, 0);
    if (NT > 1) {
      stage3(1, 0, 1);
      asm volatile("s_waitcnt vmcnt(3)" ::: "memory");   // tile0's 6 loads landed
    } else {
      asm volatile("s_waitcnt vmcnt(0)" ::: "memory");
    }
    __builtin_amdgcn_s_barrier();
    {
      const u16* s0a = &lA[0][0];
      const u16* s0b = &lB[0][0];
      #pragma unroll
      for (int mf = 0; mf < 4; ++mf) {
        af[mf][0] = *(const bf16x8*)(s0a + rA + mf * 1024 + pg0);
        af[mf][1] = *(const bf16x8*)(s0a + rA + mf * 1024 + pg1);
      }
      #pragma unroll
      for (int nf = 0; nf < 2; ++nf) {
        bfr[nf][0] = *(const bf16x8*)(s0b + rB + nf * 1024 + pg0);
        bfr[nf][1] = *(const bf16x8*)(s0b + rB + nf * 1024 + pg1);
      }
    }

    for (int kt = 0; kt < NT; ++kt) {
      const int bsel = kt & 1;
      const u16* sa  = &lA[bsel][0];
      const u16* sa1 = &lA[bsel ^ 1][0];
      const u16* sb1 = &lB[bsel ^ 1][0];

      // ---- phase 1 : mf 0..3 (X x B) ; trail: read Y(kt) ----
      if (kt + 1 < NT) stage3(bsel ^ 1, 1, kt + 1);
      __builtin_amdgcn_s_barrier();
      asm volatile("s_waitcnt lgkmcnt(0)" ::: "memory");
      __builtin_amdgcn_sched_barrier(0);
      __builtin_amdgcn_s_setprio(1);
      #pragma unroll
      for (int mf = 0; mf < 4; ++mf)
        #pragma unroll
        for (int nf = 0; nf < 2; ++nf) {
          acc[mf][nf] = __builtin_amdgcn_mfma_f32_16x16x32_bf16(bfr[nf][0], af[mf][0], acc[mf][nf], 0, 0, 0);
          acc[mf][nf] = __builtin_amdgcn_mfma_f32_16x16x32_bf16(bfr[nf][1], af[mf][1], acc[mf][nf], 0, 0, 0);
        }
      __builtin_amdgcn_s_setprio(0);
      #pragma unroll
      for (int mf = 0; mf < 4; ++mf) {
        af[mf][0] = *(const bf16x8*)(sa + rA + (mf + 4) * 1024 + pg0);
        af[mf][1] = *(const bf16x8*)(sa + rA + (mf + 4) * 1024 + pg1);
      }
      __builtin_amdgcn_sched_barrier(0);
      __builtin_amdgcn_s_barrier();

      // ---- phase 2 : mf 4..7 (Y x B) ; trail: read X(kt+1), B(kt+1) ----
      if (kt + 2 < NT) {
        stage3(bsel, 0, kt + 2);
        asm volatile("s_waitcnt vmcnt(3)" ::: "memory");  // tile kt+1 fully landed
      } else if (kt + 1 < NT) {
        asm volatile("s_waitcnt vmcnt(0)" ::: "memory");
      }
      __builtin_amdgcn_s_barrier();
      asm volatile("s_waitcnt lgkmcnt(0)" ::: "memory");
      __builtin_amdgcn_sched_barrier(0);
      __builtin_amdgcn_s_setprio(1);
      #pragma unroll
      for (int mf = 0; mf < 4; ++mf)
        #pragma unroll
        for (int nf = 0; nf < 2; ++nf) {
          acc[mf + 4][nf] = __builtin_amdgcn_mfma_f32_16x16x32_bf16(bfr[nf][0], af[mf][0], acc[mf + 4][nf], 0, 0, 0);
          acc[mf + 4][nf] = __builtin_amdgcn_mfma_f32_16x16x32_bf16(bfr[nf][1], af[mf][1], acc[mf + 4][nf], 0, 0, 0);
        }
      __builtin_amdgcn_s_setprio(0);
      if (kt + 1 < NT) {
        #pragma unroll
        for (int mf = 0; mf < 4; ++mf) {
          af[mf][0] = *(const bf16x8*)(sa1 + rA + mf * 1024 + pg0);
          af[mf][1] = *(const bf16x8*)(sa1 + rA + mf * 1024 + pg1);
        }
        #pragma unroll
        for (int nf = 0; nf < 2; ++nf) {
          bfr[nf][0] = *(const bf16x8*)(sb1 + rB + nf * 1024 + pg0);
          bfr[nf][1] = *(const bf16x8*)(sb1 + rB + nf * 1024 + pg1);
        }
      }
      __builtin_amdgcn_sched_barrier(0);
      __builtin_amdgcn_s_barrier();
    }
  }

  // ---- epilogue: swapped C/D layout -> lane holds 4 consecutive n ----
  const size_t zoff = (size_t)((long long)z * sC);
  #pragma unroll
  for (int mf = 0; mf < 8; ++mf) {
    #pragma unroll
    for (int nf = 0; nf < NF; ++nf) {
      const size_t m  = (size_t)(m0 + wr * 128 + mf * 16 + lrow);
      const size_t nc = (size_t)(n0 + wc * CPW + nf * 16 + quad * 4);
      const size_t idx = zoff + m * (size_t)ldc + nc;
      f32x4 v = acc[mf][nf];
      if constexpr (EPI == EPI_F32) {
        *(float4*)((float*)C0 + idx) = make_float4(v[0], v[1], v[2], v[3]);
      } else if constexpr (EPI == EPI_BF16) {
        ushort4 o; o.x = f2bf(v[0]); o.y = f2bf(v[1]); o.z = f2bf(v[2]); o.w = f2bf(v[3]);
        *(ushort4*)((u16*)C0 + idx) = o;
      } else if constexpr (EPI == EPI_BF16_SCALE) {
        ushort4 o;
        o.x = f2bf(v[0] * 0.03125f); o.y = f2bf(v[1] * 0.03125f);
        o.z = f2bf(v[2] * 0.03125f); o.w = f2bf(v[3] * 0.03125f);
        *(ushort4*)((u16*)C0 + idx) = o;
      } else if constexpr (EPI == EPI_BIAS_RELU_BF16) {
        const float4 bb = *(const float4*)(bias + nc);
        float y0 = v[0] + bb.x, y1 = v[1] + bb.y, y2 = v[2] + bb.z, y3 = v[3] + bb.w;
        ushort4 o;
        o.x = f2bf(y0 > 0.f ? y0 : 0.f); o.y = f2bf(y1 > 0.f ? y1 : 0.f);
        o.z = f2bf(y2 > 0.f ? y2 : 0.f); o.w = f2bf(y3 > 0.f ? y3 : 0.f);
        *(ushort4*)((u16*)C0 + idx) = o;
      } else {  // EPI_BIAS_F32
        const float4 bb = *(const float4*)(bias + nc);
        *(float4*)((float*)C0 + idx) =
            make_float4(v[0] + bb.x, v[1] + bb.y, v[2] + bb.z, v[3] + bb.w);
      }
    }
  }
}

// ---------------------------------------------------------------------------
// in-place row softmax on bf16 scores (already scaled); cols == 2048.
// Causal: skips loads past q and stores past the 256-aligned diagonal tile
// boundary (cols >= wlimit are never written by TRI nor read by clamped PV).
// ---------------------------------------------------------------------------
__global__ __launch_bounds__(256) void softmax_bf16(u16* __restrict__ SP, int causal) {
  __shared__ float red[8];
  const int row = blockIdx.x;
  const int q = row & 2047;
  u16* p = SP + (size_t)row * 2048;
  const int t = threadIdx.x;
  const int base = t * 8;
  const int limit  = causal ? (q + 1) : 2048;
  const int wlimit = causal ? (((q >> 8) + 1) << 8) : 2048;

  float v[8];
  if (base < limit) {
    uint4 raw = *(const uint4*)(p + base);
    unsigned w[4] = {raw.x, raw.y, raw.z, raw.w};
    #pragma unroll
    for (int j = 0; j < 4; j++) {
      union { unsigned u; float f; } lo, hi;
      lo.u = w[j] << 16; hi.u = w[j] & 0xffff0000u;
      v[2 * j] = lo.f; v[2 * j + 1] = hi.f;
    }
    #pragma unroll
    for (int j = 0; j < 8; j++) if (base + j >= limit) v[j] = -3.4e38f;
  } else {
    #pragma unroll
    for (int j = 0; j < 8; j++) v[j] = -3.4e38f;
  }

  float mx = v[0];
  #pragma unroll
  for (int j = 1; j < 8; j++) mx = fmaxf(mx, v[j]);
  #pragma unroll
  for (int o = 32; o > 0; o >>= 1) mx = fmaxf(mx, __shfl_down(mx, o));
  if ((t & 63) == 0) red[t >> 6] = mx;
  __syncthreads();
  mx = fmaxf(fmaxf(red[0], red[1]), fmaxf(red[2], red[3]));

  float s = 0.f;
  #pragma unroll
  for (int j = 0; j < 8; j++) { float e = __expf(v[j] - mx); v[j] = e; s += e; }
  #pragma unroll
  for (int o = 32; o > 0; o >>= 1) s += __shfl_down(s, o);
  if ((t & 63) == 0) red[4 + (t >> 6)] = s;
  __syncthreads();
  const float inv = 1.f / (red[4] + red[5] + red[6] + red[7]);

  if (base < wlimit) {
    unsigned o4[4];
    #pragma unroll
    for (int j = 0; j < 4; j++)
      o4[j] = (unsigned)f2bf(v[2 * j] * inv) | ((unsigned)f2bf(v[2 * j + 1] * inv) << 16);
    *(uint4*)(p + base) = make_uint4(o4[0], o4[1], o4[2], o4[3]);
  }
}

// ---------------------------------------------------------------------------
// LN(a + b) * g + be ; D == 1024; a bf16 (ABF=1) or f32 (ABF=0)
// ---------------------------------------------------------------------------
template <int ABF>
__global__ __launch_bounds__(256) void ln_residual(const void* __restrict__ a_,
                                                   const float* __restrict__ b,
                                                   const float* __restrict__ g,
                                                   const float* __restrict__ be,
                                                   float* __restrict__ outf,
                                                   u16* __restrict__ outb) {
  __shared__ float red[8];
  const size_t base = (size_t)blockIdx.x * 1024;
  const int t = threadIdx.x;
  const int i0 = t * 4;

  float va[4];
  if constexpr (ABF) {
    const ushort4 h = *(const ushort4*)((const u16*)a_ + base + i0);
    va[0] = bf2f(h.x); va[1] = bf2f(h.y); va[2] = bf2f(h.z); va[3] = bf2f(h.w);
  } else {
    const float4 f = *(const float4*)((const float*)a_ + base + i0);
    va[0] = f.x; va[1] = f.y; va[2] = f.z; va[3] = f.w;
  }
  const float4 vb = *(const float4*)(b + base + i0);
  float v[4] = {va[0] + vb.x, va[1] + vb.y, va[2] + vb.z, va[3] + vb.w};

  float s = v[0] + v[1] + v[2] + v[3];
  #pragma unroll
  for (int o = 32; o > 0; o >>= 1) s += __shfl_down(s, o);
  if ((t & 63) == 0) red[t >> 6] = s;
  __syncthreads();
  const float mean = (red[0] + red[1] + red[2] + red[3]) * (1.f / 1024.f);

  float qq = 0.f;
  #pragma unroll
  for (int i = 0; i < 4; i++) { float d = v[i] - mean; qq += d * d; }
  #pragma unroll
  for (int o = 32; o > 0; o >>= 1) qq += __shfl_down(qq, o);
  if ((t & 63) == 0) red[4 + (t >> 6)] = qq;
  __syncthreads();
  const float rstd = rsqrtf((red[4] + red[5] + red[6] + red[7]) * (1.f / 1024.f) + 1e-5f);

  const float4 gg = *(const float4*)(g + i0);
  const float4 bb = *(const float4*)(be + i0);
  float y0 = (v[0] - mean) * rstd * gg.x + bb.x;
  float y1 = (v[1] - mean) * rstd * gg.y + bb.y;
  float y2 = (v[2] - mean) * rstd * gg.z + bb.z;
  float y3 = (v[3] - mean) * rstd * gg.w + bb.w;
  if (outf) *(float4*)(outf + base + i0) = make_float4(y0, y1, y2, y3);
  if (outb) {
    ushort4 o4; o4.x = f2bf(y0); o4.y = f2bf(y1); o4.z = f2bf(y2); o4.w = f2bf(y3);
    *(ushort4*)(outb + base + i0) = o4;
  }
}

// ---------------------------------------------------------------------------
extern "C" void kernel_launch(void* const* d_in, const int* in_sizes, int n_in,
                              void* d_out, int out_size, void* d_ws, size_t ws_size,
                              hipStream_t stream)
{
  const float* y_in = (const float*)d_in[0];
  const float* Z_in = (const float*)d_in[1];
  const float* WQ1  = (const float*)d_in[2];
  const float* WK1  = (const float*)d_in[3];
  const float* WV1  = (const float*)d_in[4];
  const float* WQ2  = (const float*)d_in[5];
  const float* WK2  = (const float*)d_in[6];
  const float* WV2  = (const float*)d_in[7];
  const float* Wff1 = (const float*)d_in[8];
  const float* bff1 = (const float*)d_in[9];
  const float* Wff2 = (const float*)d_in[10];
  const float* bff2 = (const float*)d_in[11];
  const float* g1  = (const float*)d_in[12];
  const float* be1 = (const float*)d_in[13];
  const float* g2  = (const float*)d_in[14];
  const float* be2 = (const float*)d_in[15];
  const float* g3  = (const float*)d_in[16];
  const float* be3 = (const float*)d_in[17];
  (void)in_sizes; (void)n_in; (void)out_size;

  constexpr int Bn = 4, S = 2048, D = 1024, DF = 4096;
  constexpr long long BS = (long long)Bn * S;  // 8192 rows
  const long long SD = (long long)S * D;                 // 2M
  const long long SS = (long long)S * S;                 // 4M
  const long long SD2 = (long long)S * 2 * D;            // 4M: QKb batch stride

  char* ws = (char*)d_ws;
  size_t off = 0;
  auto alloc = [&](size_t bytes) -> char* {
    char* p = ws + off;
    off += (bytes + 255) & ~(size_t)255;
    return p;
  };

  // ---- workspace. NOTE: wq1t..wk1t must stay contiguous (merged Q|K weight
  // view for stage 1) — sizes are multiples of 256 B.
  u16* wq1t  = (u16*)alloc((size_t)D * D * 2);
  u16* wk1t  = (u16*)alloc((size_t)D * D * 2);
  u16* wv1t  = (u16*)alloc((size_t)D * D * 2);
  u16* wq2t  = (u16*)alloc((size_t)D * D * 2);
  u16* wk2t  = (u16*)alloc((size_t)D * D * 2);
  u16* wv2t  = (u16*)alloc((size_t)D * D * 2);
  u16* wff1t = (u16*)alloc((size_t)D * DF * 2);   // [4096][1024]
  u16* wff2t = (u16*)alloc((size_t)D * DF * 2);   // [1024][4096]
  u16* ybf   = (u16*)alloc((size_t)BS * D * 2);   // X1; reused as y1b after LN1
  u16* zbf   = (u16*)alloc((size_t)BS * D * 2);   // Z;  reused as y2b after LN2
  u16* QKb   = (u16*)alloc((size_t)BS * 2 * D * 2); // [8192][2048]: Q | K
  u16* Vtb   = (u16*)alloc((size_t)D * BS * 2);   // [1024][8192]: V^T, batch = col window
  u16* SPb   = (u16*)alloc((size_t)Bn * S * S * 2); // scores/probs bf16, in-place
  float* attnF = (float*)alloc((size_t)BS * D * 4); // attn out f32; reused as F
  u16*   y1b = ybf;
  u16*   y2b = zbf;
  u16*   Hb  = QKb;      // stage-3 hidden [8192][4096] overlays QKb|Vtb|SPb (dead)
  float* Fb  = attnF;

  if (off > ws_size) return;   // fail cleanly (absmax) instead of GPU fault

  const dim3 blk(256);
  const dim3 blk512(512);

  // ---- input converts + weight transposes ----
  f32_to_bf16<<<dim3((unsigned)((BS * D) / 256)), blk, 0, stream>>>(y_in, ybf, (size_t)BS * D);
  f32_to_bf16<<<dim3((unsigned)((BS * D) / 256)), blk, 0, stream>>>(Z_in, zbf, (size_t)BS * D);
  transpose_f32_bf16<<<dim3(D / 32, D / 32), blk, 0, stream>>>(WQ1, wq1t, D, D);
  transpose_f32_bf16<<<dim3(D / 32, D / 32), blk, 0, stream>>>(WK1, wk1t, D, D);
  transpose_f32_bf16<<<dim3(D / 32, D / 32), blk, 0, stream>>>(WV1, wv1t, D, D);
  transpose_f32_bf16<<<dim3(D / 32, D / 32), blk, 0, stream>>>(WQ2, wq2t, D, D);
  transpose_f32_bf16<<<dim3(D / 32, D / 32), blk, 0, stream>>>(WK2, wk2t, D, D);
  transpose_f32_bf16<<<dim3(D / 32, D / 32), blk, 0, stream>>>(WV2, wv2t, D, D);
  transpose_f32_bf16<<<dim3(DF / 32, D / 32), blk, 0, stream>>>(Wff1, wff1t, D, DF);
  transpose_f32_bf16<<<dim3(D / 32, DF / 32), blk, 0, stream>>>(Wff2, wff2t, DF, D);

  // ---- stage 1: causal self-attention + add&norm ----
  // Q|K projection: merged WQ^T||WK^T view (contiguous), C = QKb [8192][2048]
  gemm256<EPI_BF16, MODE_FULL, 256, 256><<<dim3(2 * D / 256, BS / 256, 1), blk512, 0, stream>>>(
      ybf, wq1t, QKb, nullptr, nullptr, nullptr, 0, D, D, D, 2 * D, 0, 0, 0);
  // V^T: Vt[d][s] = sum_k WvT[d][k] * X[s][k]  -> C [1024][8192]
  gemm256<EPI_BF16, MODE_FULL, 128, 256><<<dim3((unsigned)(BS / 256), D / 128, 1), blk512, 0, stream>>>(
      wv1t, ybf, Vtb, nullptr, nullptr, nullptr, 0, D, D, D, (int)BS, 0, 0, 0);
  // causal scores: lower-triangle 256x128 tiles (72/batch -> 288 blocks)
  gemm256<EPI_BF16_SCALE, MODE_TRI, 256, 128><<<dim3(72, 1, Bn), blk512, 0, stream>>>(
      QKb, QKb + D, SPb, nullptr, nullptr, nullptr, 0, D, 2 * D, 2 * D, S, SD2, SD2, SS);
  softmax_bf16<<<dim3((unsigned)(Bn * S)), blk, 0, stream>>>(SPb, 1);
  // PV: K-loop clamped to diagonal (P == 0 above it)
  gemm256<EPI_F32, MODE_CAUSAL_K, 256, 128><<<dim3(D / 128, S / 256, Bn), blk512, 0, stream>>>(
      SPb, Vtb, attnF, nullptr, nullptr, nullptr, 0, S, S, (int)BS, D, SS, S, SD);
  ln_residual<0><<<dim3((unsigned)BS), blk, 0, stream>>>(y_in, attnF, g1, be1, nullptr, y1b);

  // ---- stage 2: cross-attention + add&norm ----
  // fused Q2|K2 projection: ni<8 -> Q (y1b x wq2t), ni>=8 -> K (zbf x wk2t)
  gemm256<EPI_BF16, MODE_FULL, 256, 128><<<dim3(2 * D / 128, BS / 256, 1), blk512, 0, stream>>>(
      y1b, wq2t, QKb, nullptr, zbf, wk2t, 8, D, D, D, 2 * D, 0, 0, 0);
  gemm256<EPI_BF16, MODE_FULL, 128, 256><<<dim3((unsigned)(BS / 256), D / 128, 1), blk512, 0, stream>>>(
      wv2t, zbf, Vtb, nullptr, nullptr, nullptr, 0, D, D, D, (int)BS, 0, 0, 0);
  gemm256<EPI_BF16_SCALE, MODE_FULL, 256, 256><<<dim3(S / 256, S / 256, Bn), blk512, 0, stream>>>(
      QKb, QKb + D, SPb, nullptr, nullptr, nullptr, 0, D, 2 * D, 2 * D, S, SD2, SD2, SS);
  softmax_bf16<<<dim3((unsigned)(Bn * S)), blk, 0, stream>>>(SPb, 0);
  gemm256<EPI_F32, MODE_FULL, 256, 128><<<dim3(D / 128, S / 256, Bn), blk512, 0, stream>>>(
      SPb, Vtb, attnF, nullptr, nullptr, nullptr, 0, S, S, (int)BS, D, SS, S, SD);
  ln_residual<1><<<dim3((unsigned)BS), blk, 0, stream>>>(y1b, attnF, g2, be2, nullptr, y2b);

  // ---- stage 3: FFN + add&norm ----
  gemm256<EPI_BIAS_RELU_BF16, MODE_FULL, 256, 256><<<dim3(DF / 256, BS / 256, 1), blk512, 0, stream>>>(
      y2b, wff1t, Hb, bff1, nullptr, nullptr, 0, D, D, D, DF, 0, 0, 0);
  gemm256<EPI_BIAS_F32, MODE_FULL, 256, 128><<<dim3(D / 128, BS / 256, 1), blk512, 0, stream>>>(
      Hb, wff2t, Fb, bff2, nullptr, nullptr, 0, DF, DF, DF, D, 0, 0, 0);
  ln_residual<1><<<dim3((unsigned)BS), blk, 0, stream>>>(y2b, Fb, g3, be3, (float*)d_out, nullptr);
}

// Round 5
// 712.860 us; speedup vs baseline: 1.1469x; 1.1469x over previous
//
#include <hip/hip_runtime.h>
#include <cstddef>

typedef unsigned short u16;
typedef __attribute__((ext_vector_type(8))) short bf16x8;   // 8 bf16 in 4 VGPRs
typedef __attribute__((ext_vector_type(4))) float f32x4;

__device__ __forceinline__ u16 f2bf(float f) {
  union { float f; unsigned u; } x; x.f = f;
  unsigned r = x.u + 0x7fffu + ((x.u >> 16) & 1u);   // RNE; inputs are finite
  return (u16)(r >> 16);
}
__device__ __forceinline__ float bf2f(u16 h) {
  union { unsigned u; float f; } x; x.u = ((unsigned)h) << 16;
  return x.f;
}

// async global->LDS, 16 B per lane; LDS dest is wave-uniform base + lane*16
__device__ __forceinline__ void gll16(const u16* g, u16* ldsbase) {
  __builtin_amdgcn_global_load_lds(
      (const __attribute__((address_space(1))) void*)g,
      (__attribute__((address_space(3))) void*)ldsbase, 16, 0, 0);
}

// ---------------------------------------------------------------------------
__global__ __launch_bounds__(256) void f32_to_bf16(const float* __restrict__ in,
                                                   u16* __restrict__ out, size_t n) {
  size_t i = (size_t)blockIdx.x * 256 + threadIdx.x;
  if (i < n) out[i] = f2bf(in[i]);
}

// transpose f32 [R][C] -> bf16 [C][R]   (R,C multiples of 32) grid(C/32, R/32)
__global__ __launch_bounds__(256) void transpose_f32_bf16(const float* __restrict__ in,
                                                          u16* __restrict__ out,
                                                          int R, int C) {
  __shared__ float tile[32][33];
  int c0 = blockIdx.x * 32, r0 = blockIdx.y * 32;
  int tx = threadIdx.x & 31, ty = threadIdx.x >> 5;   // ty: 0..7
  #pragma unroll
  for (int i = ty; i < 32; i += 8)
    tile[i][tx] = in[(size_t)(r0 + i) * C + c0 + tx];
  __syncthreads();
  #pragma unroll
  for (int i = ty; i < 32; i += 8)
    out[(size_t)(c0 + i) * R + r0 + tx] = f2bf(tile[tx][i]);
}

// ---------------------------------------------------------------------------
// Tiled 8-wave GEMM: C[z][M][N] = A[z][M][K] @ Bt[z][N][K]^T, bf16 in, f32 acc.
// BK=64, 512 threads. R4: barrier-minimal schedule (R1 model: ~440 cyc per
// barrier crossing x 8/K-tile dominated; MFMA is only 2100 cyc/K-tile/SIMD).
//   256x256: 2 phases/K-tile, ONE barrier per phase (2 total, was 8).
//   256x128 / 128x256: 1 phase/K-tile, triple-buffered LDS (144 KiB).
// The pre-MFMA barrier is removable in this DMA-staged design: staging only
// ever targets regions whose readers finished in a PRIOR phase (each wave's
// reads complete before its own lgkmcnt(0) -> MFMA -> end barrier). Counted
// vmcnt per wave + end barrier gives the cross-wave tile-landed guarantee.
// Leading reads (R1 semantics; R3's trailing reads put read latency inside
// the MFMA window and regressed 84.5->102 us on FFN1 — reverted).
// MFMA K-order per acc element unchanged -> bit-identical results.
// ---------------------------------------------------------------------------
enum { EPI_F32 = 0, EPI_BF16 = 1, EPI_BF16_SCALE = 2,
       EPI_BIAS_RELU_BF16 = 3, EPI_BIAS_F32 = 4 };
enum { MODE_FULL = 0, MODE_TRI = 1, MODE_CAUSAL_K = 2 };

template <int EPI, int MODE, int BM, int BN>
__global__ __launch_bounds__(512) void gemm256(
    const u16* __restrict__ A, const u16* __restrict__ Bt,
    void* __restrict__ C0, const float* __restrict__ bias,
    const u16* __restrict__ A2, const u16* __restrict__ B2, int dsplit,
    int K, int lda, int ldb, int ldc,
    long long sA, long long sB, long long sC)
{
  constexpr int WM  = BM / 128;        // 1 or 2 M-wave groups
  constexpr int WN  = 8 / WM;          // 4 or 8 N-wave groups
  constexpr int CPW = BN / WN;         // cols per wave: 64 or 32
  constexpr int NF  = CPW / 16;        // 4 or 2 n-fragments
  constexpr int nBr = BN / 64;         // B regions (64 rows each)
  constexpr int nAr = BM / 64;         // A regions
  constexpr int NBUF = (BM == 256 && BN == 256) ? 2 : 3;

  __shared__ __align__(16) u16 lA[NBUF][BM * 64];
  __shared__ __align__(16) u16 lB[NBUF][BN * 64];

  // ---- block -> (z, mi, ni), XCD-compact swizzle (all grids %8==0) ----
  const unsigned gx = gridDim.x, gxy = gridDim.x * gridDim.y;
  unsigned id = blockIdx.x + gx * blockIdx.y + gxy * blockIdx.z;
  const unsigned nb = gxy * gridDim.z;
  unsigned p = id;
  if ((nb & 7u) == 0u) p = (id & 7u) * (nb >> 3) + (id >> 3);
  int z, mi, ni;
  if constexpr (MODE == MODE_TRI) {
    z = (int)(p / gxy);                 // gxy == tri blocks per batch
    int r = (int)(p % gxy);
    int m = 0;
    if constexpr (BN == 256) {
      while ((m + 1) * (m + 2) / 2 <= r) m++;
      mi = m; ni = r - m * (m + 1) / 2;
    } else {                            // BN=128: 2mi+2 col-tiles at row mi
      while ((m + 1) * (m + 2) <= r) m++;
      mi = m; ni = r - m * (m + 1);
    }
  } else {
    z = (int)(p / gxy);
    const unsigned rem = p % gxy;
    mi = (int)(rem / gx);
    ni = (int)(rem % gx);
  }
  // dual-source fusion (Q2+K2): upper ni half switches A/B and C offset
  if (dsplit && ni >= dsplit) {
    A = A2; Bt = B2;
    C0 = (void*)((u16*)C0 + (size_t)dsplit * BN);
    ni -= dsplit;
  }
  const int m0 = mi * BM, n0 = ni * BN;

  A  += (long long)z * sA;
  Bt += (long long)z * sB;

  int NT = K >> 6;
  if constexpr (MODE == MODE_CAUSAL_K) NT = (m0 + BM) >> 6;  // P==0 above diag

  const int t    = threadIdx.x;
  const int lane = t & 63;
  const int wave = t >> 6;
  const int wr   = (WM == 1) ? 0 : (wave >> 2);
  const int wc   = (WM == 1) ? wave : (wave & 3);
  const int quad = lane >> 4;
  const int lrow = lane & 15;

  // ---- staging addressing: pre-swizzled global source, linear LDS dest ----
  const int srow = lane >> 3;                    // 0..7 (== row & 7)
  const int scol = ((lane & 7) ^ srow) * 8;      // source granule for phys lane&7
  const u16* gAp = A  + (size_t)(m0 + wave * 8 + srow) * lda + scol;
  const u16* gBp = Bt + (size_t)(n0 + wave * 8 + srow) * ldb + scol;
  const size_t a64 = (size_t)64 * lda, b64 = (size_t)64 * ldb;
  const int lw = wave * 512;           // wave's write base within a 64-row region

  // ---- fragment read addressing (swizzled): phys granule = need ^ (row&7) ----
  const int pg0 = (quad ^ (lrow & 7)) * 8;       // ks=0
  const int pg1 = pg0 ^ 32;                      // ks=1
  const int rA = (wr * 128 + lrow) * 64;
  const int rB = (wc * CPW + lrow) * 64;

  f32x4 acc[8][NF];
  const f32x4 zero = {0.f, 0.f, 0.f, 0.f};
  #pragma unroll
  for (int i = 0; i < 8; i++)
    #pragma unroll
    for (int j = 0; j < NF; j++) acc[i][j] = zero;

  bf16x8 X[4][2];      // A rows wr*128 + 0..63
  bf16x8 Y[4][2];      // A rows wr*128 + 64..127
  bf16x8 bfr[NF][2];   // B frags

  auto rdX = [&](const u16* s) {
    #pragma unroll
    for (int mf = 0; mf < 4; ++mf) {
      X[mf][0] = *(const bf16x8*)(s + rA + mf * 1024 + pg0);
      X[mf][1] = *(const bf16x8*)(s + rA + mf * 1024 + pg1);
    }
  };
  auto rdY = [&](const u16* s) {
    #pragma unroll
    for (int mf = 0; mf < 4; ++mf) {
      Y[mf][0] = *(const bf16x8*)(s + rA + (mf + 4) * 1024 + pg0);
      Y[mf][1] = *(const bf16x8*)(s + rA + (mf + 4) * 1024 + pg1);
    }
  };
  auto rdB = [&](const u16* s) {
    #pragma unroll
    for (int nf = 0; nf < NF; ++nf) {
      bfr[nf][0] = *(const bf16x8*)(s + rB + nf * 1024 + pg0);
      bfr[nf][1] = *(const bf16x8*)(s + rB + nf * 1024 + pg1);
    }
  };

  if constexpr (NBUF == 2) {
    // ================= 256x256 : 2 phases / K-tile, 1 barrier each =========
    auto stageB2 = [&](int b, int kt) {
      const int k = kt * 64;
      gll16(gBp + k,           &lB[b][lw]);
      gll16(gBp + k + b64,     &lB[b][4096 + lw]);
      gll16(gBp + k + 2 * b64, &lB[b][8192 + lw]);
      gll16(gBp + k + 3 * b64, &lB[b][12288 + lw]);
    };
    auto stageA2 = [&](int b, int kt) {
      const int k = kt * 64;
      gll16(gAp + k,           &lA[b][lw]);
      gll16(gAp + k + a64,     &lA[b][4096 + lw]);
      gll16(gAp + k + 2 * a64, &lA[b][8192 + lw]);
      gll16(gAp + k + 3 * a64, &lA[b][12288 + lw]);
    };

    stageB2(0, 0); stageA2(0, 0);
    if (NT > 1) {
      stageB2(1, 1);
      asm volatile("s_waitcnt vmcnt(4)" ::: "memory");   // tile0's 8 landed
    } else {
      asm volatile("s_waitcnt vmcnt(0)" ::: "memory");
    }
    __builtin_amdgcn_s_barrier();

    for (int kt = 0; kt < NT; ++kt) {
      const int bsel = kt & 1;
      const u16* sa = &lA[bsel][0];
      const u16* sb = &lB[bsel][0];

      // ---- phase A : Q(0,*) = X x B[0..3] ----
      rdX(sa); rdB(sb);
      if (kt + 1 < NT) stageA2(bsel ^ 1, kt + 1);   // overwrites tile kt-1 A
      asm volatile("s_waitcnt lgkmcnt(0)" ::: "memory");
      __builtin_amdgcn_sched_barrier(0);
      __builtin_amdgcn_s_setprio(1);
      #pragma unroll
      for (int mf = 0; mf < 4; ++mf)
        #pragma unroll
        for (int nf = 0; nf < 4; ++nf) {
          acc[mf][nf] = __builtin_amdgcn_mfma_f32_16x16x32_bf16(bfr[nf][0], X[mf][0], acc[mf][nf], 0, 0, 0);
          acc[mf][nf] = __builtin_amdgcn_mfma_f32_16x16x32_bf16(bfr[nf][1], X[mf][1], acc[mf][nf], 0, 0, 0);
        }
      __builtin_amdgcn_s_setprio(0);
      __builtin_amdgcn_s_barrier();   // A-reads done (own lgkm) before B-stage

      // ---- phase B : Q(1,*) = Y x B[0..3] ----
      rdY(sa);
      if (kt + 2 < NT) stageB2(bsel, kt + 2);       // overwrites tile kt B
      asm volatile("s_waitcnt lgkmcnt(0)" ::: "memory");
      __builtin_amdgcn_sched_barrier(0);
      __builtin_amdgcn_s_setprio(1);
      #pragma unroll
      for (int mf = 0; mf < 4; ++mf)
        #pragma unroll
        for (int nf = 0; nf < 4; ++nf) {
          acc[mf + 4][nf] = __builtin_amdgcn_mfma_f32_16x16x32_bf16(bfr[nf][0], Y[mf][0], acc[mf + 4][nf], 0, 0, 0);
          acc[mf + 4][nf] = __builtin_amdgcn_mfma_f32_16x16x32_bf16(bfr[nf][1], Y[mf][1], acc[mf + 4][nf], 0, 0, 0);
        }
      __builtin_amdgcn_s_setprio(0);
      // vmcnt(4): newest 4 = B(kt+2); A(kt+1) + older B(kt+1) retired ->
      // tile kt+1 fully in LDS for next phase A (barrier orders all waves).
      if (kt + 2 < NT)      asm volatile("s_waitcnt vmcnt(4)" ::: "memory");
      else if (kt + 1 < NT) asm volatile("s_waitcnt vmcnt(0)" ::: "memory");
      __builtin_amdgcn_s_barrier();
    }
  } else {
    // ====== narrow (256x128 / 128x256) : 1 phase / K-tile, 3 LDS buffers ===
    u16 *a0 = &lA[0][0], *a1 = &lA[1][0], *a2 = &lA[2][0];
    u16 *b0 = &lB[0][0], *b1 = &lB[1][0], *b2 = &lB[2][0];
    auto stage6 = [&](u16* ba, u16* bb, int kt) {
      const int k = kt * 64;
      #pragma unroll
      for (int s = 0; s < nBr; ++s)
        gll16(gBp + k + (size_t)s * b64, bb + s * 4096 + lw);
      #pragma unroll
      for (int s = 0; s < nAr; ++s)
        gll16(gAp + k + (size_t)s * a64, ba + s * 4096 + lw);
    };

    stage6(a0, b0, 0);
    if (NT > 1) {
      stage6(a1, b1, 1);
      asm volatile("s_waitcnt vmcnt(6)" ::: "memory");   // tile0's 6 landed
    } else {
      asm volatile("s_waitcnt vmcnt(0)" ::: "memory");
    }
    __builtin_amdgcn_s_barrier();

    for (int kt = 0; kt < NT; ++kt) {
      rdX(a0); rdY(a0); rdB(b0);                    // tile kt (20 reads)
      if (kt + 2 < NT) stage6(a2, b2, kt + 2);      // a2/b2 hold tile kt-1 (dead)
      asm volatile("s_waitcnt lgkmcnt(0)" ::: "memory");
      __builtin_amdgcn_sched_barrier(0);
      __builtin_amdgcn_s_setprio(1);
      #pragma unroll
      for (int mf = 0; mf < 4; ++mf)
        #pragma unroll
        for (int nf = 0; nf < 2; ++nf) {
          acc[mf][nf] = __builtin_amdgcn_mfma_f32_16x16x32_bf16(bfr[nf][0], X[mf][0], acc[mf][nf], 0, 0, 0);
          acc[mf][nf] = __builtin_amdgcn_mfma_f32_16x16x32_bf16(bfr[nf][1], X[mf][1], acc[mf][nf], 0, 0, 0);
        }
      #pragma unroll
      for (int mf = 0; mf < 4; ++mf)
        #pragma unroll
        for (int nf = 0; nf < 2; ++nf) {
          acc[mf + 4][nf] = __builtin_amdgcn_mfma_f32_16x16x32_bf16(bfr[nf][0], Y[mf][0], acc[mf + 4][nf], 0, 0, 0);
          acc[mf + 4][nf] = __builtin_amdgcn_mfma_f32_16x16x32_bf16(bfr[nf][1], Y[mf][1], acc[mf + 4][nf], 0, 0, 0);
        }
      __builtin_amdgcn_s_setprio(0);
      // vmcnt(6): newest 6 = tile kt+2; tile kt+1 retired -> readable next phase
      if (kt + 2 < NT)      asm volatile("s_waitcnt vmcnt(6)" ::: "memory");
      else if (kt + 1 < NT) asm volatile("s_waitcnt vmcnt(0)" ::: "memory");
      __builtin_amdgcn_s_barrier();
      u16* tp;
      tp = a0; a0 = a1; a1 = a2; a2 = tp;
      tp = b0; b0 = b1; b1 = b2; b2 = tp;
    }
  }

  // ---- epilogue: swapped C/D layout -> lane holds 4 consecutive n ----
  const size_t zoff = (size_t)((long long)z * sC);
  #pragma unroll
  for (int mf = 0; mf < 8; ++mf) {
    #pragma unroll
    for (int nf = 0; nf < NF; ++nf) {
      const size_t m  = (size_t)(m0 + wr * 128 + mf * 16 + lrow);
      const size_t nc = (size_t)(n0 + wc * CPW + nf * 16 + quad * 4);
      const size_t idx = zoff + m * (size_t)ldc + nc;
      f32x4 v = acc[mf][nf];
      if constexpr (EPI == EPI_F32) {
        *(float4*)((float*)C0 + idx) = make_float4(v[0], v[1], v[2], v[3]);
      } else if constexpr (EPI == EPI_BF16) {
        ushort4 o; o.x = f2bf(v[0]); o.y = f2bf(v[1]); o.z = f2bf(v[2]); o.w = f2bf(v[3]);
        *(ushort4*)((u16*)C0 + idx) = o;
      } else if constexpr (EPI == EPI_BF16_SCALE) {
        ushort4 o;
        o.x = f2bf(v[0] * 0.03125f); o.y = f2bf(v[1] * 0.03125f);
        o.z = f2bf(v[2] * 0.03125f); o.w = f2bf(v[3] * 0.03125f);
        *(ushort4*)((u16*)C0 + idx) = o;
      } else if constexpr (EPI == EPI_BIAS_RELU_BF16) {
        const float4 bb = *(const float4*)(bias + nc);
        float y0 = v[0] + bb.x, y1 = v[1] + bb.y, y2 = v[2] + bb.z, y3 = v[3] + bb.w;
        ushort4 o;
        o.x = f2bf(y0 > 0.f ? y0 : 0.f); o.y = f2bf(y1 > 0.f ? y1 : 0.f);
        o.z = f2bf(y2 > 0.f ? y2 : 0.f); o.w = f2bf(y3 > 0.f ? y3 : 0.f);
        *(ushort4*)((u16*)C0 + idx) = o;
      } else {  // EPI_BIAS_F32
        const float4 bb = *(const float4*)(bias + nc);
        *(float4*)((float*)C0 + idx) =
            make_float4(v[0] + bb.x, v[1] + bb.y, v[2] + bb.z, v[3] + bb.w);
      }
    }
  }
}

// ---------------------------------------------------------------------------
// in-place row softmax on bf16 scores (already scaled); cols == 2048.
// Causal: skips loads past q and stores past the 256-aligned diagonal tile
// boundary (cols >= wlimit are never written by TRI nor read by clamped PV).
// ---------------------------------------------------------------------------
__global__ __launch_bounds__(256) void softmax_bf16(u16* __restrict__ SP, int causal) {
  __shared__ float red[8];
  const int row = blockIdx.x;
  const int q = row & 2047;
  u16* p = SP + (size_t)row * 2048;
  const int t = threadIdx.x;
  const int base = t * 8;
  const int limit  = causal ? (q + 1) : 2048;
  const int wlimit = causal ? (((q >> 8) + 1) << 8) : 2048;

  float v[8];
  if (base < limit) {
    uint4 raw = *(const uint4*)(p + base);
    unsigned w[4] = {raw.x, raw.y, raw.z, raw.w};
    #pragma unroll
    for (int j = 0; j < 4; j++) {
      union { unsigned u; float f; } lo, hi;
      lo.u = w[j] << 16; hi.u = w[j] & 0xffff0000u;
      v[2 * j] = lo.f; v[2 * j + 1] = hi.f;
    }
    #pragma unroll
    for (int j = 0; j < 8; j++) if (base + j >= limit) v[j] = -3.4e38f;
  } else {
    #pragma unroll
    for (int j = 0; j < 8; j++) v[j] = -3.4e38f;
  }

  float mx = v[0];
  #pragma unroll
  for (int j = 1; j < 8; j++) mx = fmaxf(mx, v[j]);
  #pragma unroll
  for (int o = 32; o > 0; o >>= 1) mx = fmaxf(mx, __shfl_down(mx, o));
  if ((t & 63) == 0) red[t >> 6] = mx;
  __syncthreads();
  mx = fmaxf(fmaxf(red[0], red[1]), fmaxf(red[2], red[3]));

  float s = 0.f;
  #pragma unroll
  for (int j = 0; j < 8; j++) { float e = __expf(v[j] - mx); v[j] = e; s += e; }
  #pragma unroll
  for (int o = 32; o > 0; o >>= 1) s += __shfl_down(s, o);
  if ((t & 63) == 0) red[4 + (t >> 6)] = s;
  __syncthreads();
  const float inv = 1.f / (red[4] + red[5] + red[6] + red[7]);

  if (base < wlimit) {
    unsigned o4[4];
    #pragma unroll
    for (int j = 0; j < 4; j++)
      o4[j] = (unsigned)f2bf(v[2 * j] * inv) | ((unsigned)f2bf(v[2 * j + 1] * inv) << 16);
    *(uint4*)(p + base) = make_uint4(o4[0], o4[1], o4[2], o4[3]);
  }
}

// ---------------------------------------------------------------------------
// LN(a + b) * g + be ; D == 1024; a bf16 (ABF=1) or f32 (ABF=0)
// ---------------------------------------------------------------------------
template <int ABF>
__global__ __launch_bounds__(256) void ln_residual(const void* __restrict__ a_,
                                                   const float* __restrict__ b,
                                                   const float* __restrict__ g,
                                                   const float* __restrict__ be,
                                                   float* __restrict__ outf,
                                                   u16* __restrict__ outb) {
  __shared__ float red[8];
  const size_t base = (size_t)blockIdx.x * 1024;
  const int t = threadIdx.x;
  const int i0 = t * 4;

  float va[4];
  if constexpr (ABF) {
    const ushort4 h = *(const ushort4*)((const u16*)a_ + base + i0);
    va[0] = bf2f(h.x); va[1] = bf2f(h.y); va[2] = bf2f(h.z); va[3] = bf2f(h.w);
  } else {
    const float4 f = *(const float4*)((const float*)a_ + base + i0);
    va[0] = f.x; va[1] = f.y; va[2] = f.z; va[3] = f.w;
  }
  const float4 vb = *(const float4*)(b + base + i0);
  float v[4] = {va[0] + vb.x, va[1] + vb.y, va[2] + vb.z, va[3] + vb.w};

  float s = v[0] + v[1] + v[2] + v[3];
  #pragma unroll
  for (int o = 32; o > 0; o >>= 1) s += __shfl_down(s, o);
  if ((t & 63) == 0) red[t >> 6] = s;
  __syncthreads();
  const float mean = (red[0] + red[1] + red[2] + red[3]) * (1.f / 1024.f);

  float qq = 0.f;
  #pragma unroll
  for (int i = 0; i < 4; i++) { float d = v[i] - mean; qq += d * d; }
  #pragma unroll
  for (int o = 32; o > 0; o >>= 1) qq += __shfl_down(qq, o);
  if ((t & 63) == 0) red[4 + (t >> 6)] = qq;
  __syncthreads();
  const float rstd = rsqrtf((red[4] + red[5] + red[6] + red[7]) * (1.f / 1024.f) + 1e-5f);

  const float4 gg = *(const float4*)(g + i0);
  const float4 bb = *(const float4*)(be + i0);
  float y0 = (v[0] - mean) * rstd * gg.x + bb.x;
  float y1 = (v[1] - mean) * rstd * gg.y + bb.y;
  float y2 = (v[2] - mean) * rstd * gg.z + bb.z;
  float y3 = (v[3] - mean) * rstd * gg.w + bb.w;
  if (outf) *(float4*)(outf + base + i0) = make_float4(y0, y1, y2, y3);
  if (outb) {
    ushort4 o4; o4.x = f2bf(y0); o4.y = f2bf(y1); o4.z = f2bf(y2); o4.w = f2bf(y3);
    *(ushort4*)(outb + base + i0) = o4;
  }
}

// ---------------------------------------------------------------------------
extern "C" void kernel_launch(void* const* d_in, const int* in_sizes, int n_in,
                              void* d_out, int out_size, void* d_ws, size_t ws_size,
                              hipStream_t stream)
{
  const float* y_in = (const float*)d_in[0];
  const float* Z_in = (const float*)d_in[1];
  const float* WQ1  = (const float*)d_in[2];
  const float* WK1  = (const float*)d_in[3];
  const float* WV1  = (const float*)d_in[4];
  const float* WQ2  = (const float*)d_in[5];
  const float* WK2  = (const float*)d_in[6];
  const float* WV2  = (const float*)d_in[7];
  const float* Wff1 = (const float*)d_in[8];
  const float* bff1 = (const float*)d_in[9];
  const float* Wff2 = (const float*)d_in[10];
  const float* bff2 = (const float*)d_in[11];
  const float* g1  = (const float*)d_in[12];
  const float* be1 = (const float*)d_in[13];
  const float* g2  = (const float*)d_in[14];
  const float* be2 = (const float*)d_in[15];
  const float* g3  = (const float*)d_in[16];
  const float* be3 = (const float*)d_in[17];
  (void)in_sizes; (void)n_in; (void)out_size;

  constexpr int Bn = 4, S = 2048, D = 1024, DF = 4096;
  constexpr long long BS = (long long)Bn * S;  // 8192 rows
  const long long SD = (long long)S * D;                 // 2M
  const long long SS = (long long)S * S;                 // 4M
  const long long SD2 = (long long)S * 2 * D;            // 4M: QKb batch stride

  char* ws = (char*)d_ws;
  size_t off = 0;
  auto alloc = [&](size_t bytes) -> char* {
    char* p = ws + off;
    off += (bytes + 255) & ~(size_t)255;
    return p;
  };

  // ---- workspace. NOTE: wq1t..wk1t must stay contiguous (merged Q|K weight
  // view for stage 1) — sizes are multiples of 256 B.
  u16* wq1t  = (u16*)alloc((size_t)D * D * 2);
  u16* wk1t  = (u16*)alloc((size_t)D * D * 2);
  u16* wv1t  = (u16*)alloc((size_t)D * D * 2);
  u16* wq2t  = (u16*)alloc((size_t)D * D * 2);
  u16* wk2t  = (u16*)alloc((size_t)D * D * 2);
  u16* wv2t  = (u16*)alloc((size_t)D * D * 2);
  u16* wff1t = (u16*)alloc((size_t)D * DF * 2);   // [4096][1024]
  u16* wff2t = (u16*)alloc((size_t)D * DF * 2);   // [1024][4096]
  u16* ybf   = (u16*)alloc((size_t)BS * D * 2);   // X1; reused as y1b after LN1
  u16* zbf   = (u16*)alloc((size_t)BS * D * 2);   // Z;  reused as y2b after LN2
  u16* QKb   = (u16*)alloc((size_t)BS * 2 * D * 2); // [8192][2048]: Q | K
  u16* Vtb   = (u16*)alloc((size_t)D * BS * 2);   // [1024][8192]: V^T, batch = col window
  u16* SPb   = (u16*)alloc((size_t)Bn * S * S * 2); // scores/probs bf16, in-place
  float* attnF = (float*)alloc((size_t)BS * D * 4); // attn out f32; reused as F
  u16*   y1b = ybf;
  u16*   y2b = zbf;
  u16*   Hb  = QKb;      // stage-3 hidden [8192][4096] overlays QKb|Vtb|SPb (dead)
  float* Fb  = attnF;

  if (off > ws_size) return;   // fail cleanly (absmax) instead of GPU fault

  const dim3 blk(256);
  const dim3 blk512(512);

  // ---- input converts + weight transposes ----
  f32_to_bf16<<<dim3((unsigned)((BS * D) / 256)), blk, 0, stream>>>(y_in, ybf, (size_t)BS * D);
  f32_to_bf16<<<dim3((unsigned)((BS * D) / 256)), blk, 0, stream>>>(Z_in, zbf, (size_t)BS * D);
  transpose_f32_bf16<<<dim3(D / 32, D / 32), blk, 0, stream>>>(WQ1, wq1t, D, D);
  transpose_f32_bf16<<<dim3(D / 32, D / 32), blk, 0, stream>>>(WK1, wk1t, D, D);
  transpose_f32_bf16<<<dim3(D / 32, D / 32), blk, 0, stream>>>(WV1, wv1t, D, D);
  transpose_f32_bf16<<<dim3(D / 32, D / 32), blk, 0, stream>>>(WQ2, wq2t, D, D);
  transpose_f32_bf16<<<dim3(D / 32, D / 32), blk, 0, stream>>>(WK2, wk2t, D, D);
  transpose_f32_bf16<<<dim3(D / 32, D / 32), blk, 0, stream>>>(WV2, wv2t, D, D);
  transpose_f32_bf16<<<dim3(DF / 32, D / 32), blk, 0, stream>>>(Wff1, wff1t, D, DF);
  transpose_f32_bf16<<<dim3(D / 32, DF / 32), blk, 0, stream>>>(Wff2, wff2t, DF, D);

  // ---- stage 1: causal self-attention + add&norm ----
  // Q|K projection: merged WQ^T||WK^T view (contiguous), C = QKb [8192][2048]
  gemm256<EPI_BF16, MODE_FULL, 256, 256><<<dim3(2 * D / 256, BS / 256, 1), blk512, 0, stream>>>(
      ybf, wq1t, QKb, nullptr, nullptr, nullptr, 0, D, D, D, 2 * D, 0, 0, 0);
  // V^T: Vt[d][s] = sum_k WvT[d][k] * X[s][k]  -> C [1024][8192]
  gemm256<EPI_BF16, MODE_FULL, 128, 256><<<dim3((unsigned)(BS / 256), D / 128, 1), blk512, 0, stream>>>(
      wv1t, ybf, Vtb, nullptr, nullptr, nullptr, 0, D, D, D, (int)BS, 0, 0, 0);
  // causal scores: lower-triangle 256x128 tiles (72/batch -> 288 blocks)
  gemm256<EPI_BF16_SCALE, MODE_TRI, 256, 128><<<dim3(72, 1, Bn), blk512, 0, stream>>>(
      QKb, QKb + D, SPb, nullptr, nullptr, nullptr, 0, D, 2 * D, 2 * D, S, SD2, SD2, SS);
  softmax_bf16<<<dim3((unsigned)(Bn * S)), blk, 0, stream>>>(SPb, 1);
  // PV: K-loop clamped to diagonal (P == 0 above it)
  gemm256<EPI_F32, MODE_CAUSAL_K, 256, 128><<<dim3(D / 128, S / 256, Bn), blk512, 0, stream>>>(
      SPb, Vtb, attnF, nullptr, nullptr, nullptr, 0, S, S, (int)BS, D, SS, S, SD);
  ln_residual<0><<<dim3((unsigned)BS), blk, 0, stream>>>(y_in, attnF, g1, be1, nullptr, y1b);

  // ---- stage 2: cross-attention + add&norm ----
  // fused Q2|K2 projection: ni<8 -> Q (y1b x wq2t), ni>=8 -> K (zbf x wk2t)
  gemm256<EPI_BF16, MODE_FULL, 256, 128><<<dim3(2 * D / 128, BS / 256, 1), blk512, 0, stream>>>(
      y1b, wq2t, QKb, nullptr, zbf, wk2t, 8, D, D, D, 2 * D, 0, 0, 0);
  gemm256<EPI_BF16, MODE_FULL, 128, 256><<<dim3((unsigned)(BS / 256), D / 128, 1), blk512, 0, stream>>>(
      wv2t, zbf, Vtb, nullptr, nullptr, nullptr, 0, D, D, D, (int)BS, 0, 0, 0);
  gemm256<EPI_BF16_SCALE, MODE_FULL, 256, 256><<<dim3(S / 256, S / 256, Bn), blk512, 0, stream>>>(
      QKb, QKb + D, SPb, nullptr, nullptr, nullptr, 0, D, 2 * D, 2 * D, S, SD2, SD2, SS);
  softmax_bf16<<<dim3((unsigned)(Bn * S)), blk, 0, stream>>>(SPb, 0);
  gemm256<EPI_F32, MODE_FULL, 256, 128><<<dim3(D / 128, S / 256, Bn), blk512, 0, stream>>>(
      SPb, Vtb, attnF, nullptr, nullptr, nullptr, 0, S, S, (int)BS, D, SS, S, SD);
  ln_residual<1><<<dim3((unsigned)BS), blk, 0, stream>>>(y1b, attnF, g2, be2, nullptr, y2b);

  // ---- stage 3: FFN + add&norm ----
  gemm256<EPI_BIAS_RELU_BF16, MODE_FULL, 256, 256><<<dim3(DF / 256, BS / 256, 1), blk512, 0, stream>>>(
      y2b, wff1t, Hb, bff1, nullptr, nullptr, 0, D, D, D, DF, 0, 0, 0);
  gemm256<EPI_BIAS_F32, MODE_FULL, 256, 128><<<dim3(D / 128, BS / 256, 1), blk512, 0, stream>>>(
      Hb, wff2t, Fb, bff2, nullptr, nullptr, 0, DF, DF, DF, D, 0, 0, 0);
  ln_residual<1><<<dim3((unsigned)BS), blk, 0, stream>>>(y2b, Fb, g3, be3, (float*)d_out, nullptr);
}